// Round 2
// baseline (26463.116 us; speedup 1.0000x reference)
//
#include <hip/hip_runtime.h>

// R4: XCD-local FLAGS, system-scope DATA.
//
// Post-mortem of R3 (absmax 0.57 corruption): the full-L2 FAST protocol
// relied on (a) blockIdx%8 -> XCD placement and (b) vmcnt(0) acking sc0
// stores at L2-commit. The probe tested neither. R4 keeps every DATA-path
// byte identical to the R2-proven 13.26ms kernel (h publishes/loads and the
// vmcnt(0) drain are sc0 sc1 / IF$-ordered), and moves ONLY the flag hop
// into the XCD-shared L2 (sc0). Flag is stored after the proven IF$ drain,
// so "flag seen => data at IF$" needs no new ordering assumption — only
// sc0-store -> sc0-load visibility through the shared L2, which is:
//   1) guaranteed structurally: membership comes from s_getreg(XCC_ID)
//      ticketing (ground-truth co-residency, no placement heuristic);
//   2) verified by a two-generation, epoch-keyed probe (catches stale L1/L2
//      lines and non-propagating stores), with a system-scope verdict vote
//      falling back to the R2 protocol on any anomaly.

typedef _Float16 half8 __attribute__((ext_vector_type(8)));
typedef float f32x4 __attribute__((ext_vector_type(4)));

#define B_ 32
#define S_ 2048
#define D_ 256
#define H_ 256
#define G_ 1024
#define NSLOT 8
#define OUT0 (B_*S_*2*H_)   /* 33554432 */

// hbuf geometry (per region: [2 layers][NSLOT][16 rows][256] f16)
#define HB_SLOT   (16*H_)            /* 4096 f16 */
#define HB_LAYER  (NSLOT*HB_SLOT)    /* 32768 f16 */
#define HB_REGION (2*HB_LAYER)       /* 65536 f16 */

__device__ __forceinline__ float sigmoidf_(float v){ return 1.f/(1.f+__expf(-v)); }
__device__ __forceinline__ float tanhf_(float v){ return 2.f/(1.f+__expf(-2.f*v)) - 1.f; }

union H8U { half8 h; unsigned u[4]; };

// R2-proven system-scope 16B coherent load (4 relaxed system atomics; the
// compiler inserts the vmcnt waits before use).
__device__ __forceinline__ half8 ld_h8_sys(const _Float16* p) {
  const unsigned* u = (const unsigned*)p;
  H8U r;
  r.u[0] = __hip_atomic_load(u+0, __ATOMIC_RELAXED, __HIP_MEMORY_SCOPE_SYSTEM);
  r.u[1] = __hip_atomic_load(u+1, __ATOMIC_RELAXED, __HIP_MEMORY_SCOPE_SYSTEM);
  r.u[2] = __hip_atomic_load(u+2, __ATOMIC_RELAXED, __HIP_MEMORY_SCOPE_SYSTEM);
  r.u[3] = __hip_atomic_load(u+3, __ATOMIC_RELAXED, __HIP_MEMORY_SCOPE_SYSTEM);
  return r.h;
}

// FAST (XCD-L2) flag primitives: sc0 = bypass L1, served by the shared L2.
__device__ __forceinline__ int ld_flag_fast(const int* p) {
  int v;
  asm volatile("global_load_dword %0, %1, off sc0\n\ts_waitcnt vmcnt(0)"
               : "=v"(v) : "v"(p) : "memory");
  return v;
}
__device__ __forceinline__ void st_dw_fast(unsigned* p, unsigned v) {
  asm volatile("global_store_dword %0, %1, off sc0" :: "v"(p), "v"(v) : "memory");
}

template<bool FFAST>
__device__ __forceinline__ int flag_poll(const int* p) {
  if constexpr (FFAST) return ld_flag_fast(p);
  else return __hip_atomic_load(p, __ATOMIC_RELAXED, __HIP_MEMORY_SCOPE_SYSTEM);
}
template<bool FFAST>
__device__ __forceinline__ void flag_raise(int* p, int v) {
  if constexpr (FFAST) st_dw_fast((unsigned*)p, (unsigned)v);
  else __hip_atomic_store(p, v, __ATOMIC_RELAXED, __HIP_MEMORY_SCOPE_SYSTEM);
}

// ws layout: [0,8K): flags (4 regions * 32 members, 64B stride)
//            [8K): cnt[8]  [8448): epoch  [8704): toks[128]  [9728): verd[128]
//            [32K, 32K+512K): hbuf
__global__ __launch_bounds__(256) void lstm_prep(const float* __restrict__ enc_h,
                                                 int* __restrict__ flags,
                                                 int* __restrict__ cnt,
                                                 int* __restrict__ epoch,
                                                 int* __restrict__ toks,
                                                 int* __restrict__ verd,
                                                 _Float16* __restrict__ hbuf)
{
  int idx = blockIdx.x*blockDim.x + threadIdx.x;
  if (idx == 0)
    __hip_atomic_fetch_add(epoch, 1, __ATOMIC_RELAXED, __HIP_MEMORY_SCOPE_SYSTEM);
  if (idx < 128) {
    __hip_atomic_store(&flags[idx*16], 0, __ATOMIC_RELAXED, __HIP_MEMORY_SCOPE_SYSTEM);
    __hip_atomic_store(&toks[idx], 0,  __ATOMIC_RELAXED, __HIP_MEMORY_SCOPE_SYSTEM);
    __hip_atomic_store(&verd[idx], -1, __ATOMIC_RELAXED, __HIP_MEMORY_SCOPE_SYSTEM);
  }
  if (idx < 8)
    __hip_atomic_store(&cnt[idx], 0, __ATOMIC_RELAXED, __HIP_MEMORY_SCOPE_SYSTEM);

  // h(t=0) init: slot 0 of both layers, 4 regions (16384 dwords).
  for (int j = idx; j < 4*2*16*128; j += gridDim.x*blockDim.x) {
    int c2     = j & 127;
    int row    = (j >> 7) & 15;
    int layer  = (j >> 11) & 1;
    int region = j >> 12;            // 0..3
    int m   = region & 1;
    int dir = region >> 1;
    int b   = m*16 + row;
    int col = c2*2;
    _Float16 lo = (_Float16)enc_h[b*(2*H_) + dir*H_ + col];
    _Float16 hi = (_Float16)enc_h[b*(2*H_) + dir*H_ + col + 1];
    unsigned u = (unsigned)__builtin_bit_cast(unsigned short, lo)
               | ((unsigned)__builtin_bit_cast(unsigned short, hi) << 16);
    __hip_atomic_store((unsigned*)(hbuf + (size_t)region*HB_REGION
                                   + (size_t)layer*HB_LAYER + row*H_ + col), u,
                       __ATOMIC_RELAXED, __HIP_MEMORY_SCOPE_SYSTEM);
  }
}

template<bool FFAST>
__device__ __forceinline__ void run_lstm(
    const float* __restrict__ x,
    const float* __restrict__ enc_c,
    const float* __restrict__ Wih, const float* __restrict__ Whh,
    const float* __restrict__ bih, const float* __restrict__ bhh,
    float* __restrict__ out,
    int* __restrict__ flags,
    _Float16* __restrict__ hbuf,
    int region, int member)
{
  const int dir   = region >> 1;
  const int m     = region & 1;
  const int layer = member & 1;
  const int c0    = (member >> 1) << 4;   // h-column base (16 cols)
  const int lane  = threadIdx.x;          // 64
  const int quad  = lane >> 4;
  const int lq    = lane & 15;

  // ---- resident B-fragments: bf[q][kk], q=gate(i,f,g,o), kk=K-frag ----
  half8 bf[4][16];
#pragma unroll
  for (int q = 0; q < 4; ++q) {
    const int n_g = q*256 + c0 + lq;
    const float* wihr = Wih + (size_t)layer*G_*256 + (size_t)n_g*256 + quad*8;
    const float* whhr = Whh + (size_t)layer*G_*256 + (size_t)n_g*256 + quad*8;
#pragma unroll
    for (int kk = 0; kk < 16; ++kk) {
      const float* src = (kk < 8) ? (wihr + kk*32) : (whhr + (kk-8)*32);
      f32x4 w0 = *(const f32x4*)src;
      f32x4 w1 = *(const f32x4*)(src+4);
      half8 hv;
      hv[0]=(_Float16)w0[0]; hv[1]=(_Float16)w0[1]; hv[2]=(_Float16)w0[2]; hv[3]=(_Float16)w0[3];
      hv[4]=(_Float16)w1[0]; hv[5]=(_Float16)w1[1]; hv[6]=(_Float16)w1[2]; hv[7]=(_Float16)w1[3];
      bf[q][kk] = hv;
    }
  }

  float bias[4];
#pragma unroll
  for (int q = 0; q < 4; ++q) {
    const int n_g = q*256 + c0 + lq;
    bias[q] = bih[layer*G_ + n_g] + bhh[layer*G_ + n_g];
  }

  // c-state in C/D layout: row = m*16 + quad*4 + r, col = c0+lq
  f32x4 cst;
#pragma unroll
  for (int r = 0; r < 4; ++r) {
    const int b = m*16 + quad*4 + r;
    cst[r] = enc_c[b*(2*H_) + dir*H_ + c0 + lq];
  }

  _Float16* hbR          = hbuf + (size_t)region*HB_REGION;
  _Float16* hbufOwn      = hbR + (size_t)layer*HB_LAYER;
  const _Float16* hbufL0 = hbR;                       // layer-0 buffer
  int* flagsR = flags + region*(32*16);
  int* myFlag = flagsR + member*16;

  // Poll set: grp0 lanes cover the 16 same-layer members (own recurrence),
  // grp1 lanes cover the 16 other-layer members (producer / backpressure).
  const int c16 = lane & 15;
  const int grp = (lane >> 4) & 1;
  const int spinLayer = grp ? (layer ^ 1) : layer;
  const int* spinPtr = flagsR + (c16*2 + spinLayer)*16;
  // L0: own >= t, L1(consumer) >= t-7 (slot backpressure)
  // L1: own >= t, L0(producer) >= t+1 (h0(t) published)
  const int tgtOff = (layer == 0) ? (grp ? -7 : 0) : (grp ? 1 : 0);

  const int arow = m*16 + lq;              // global batch row this lane feeds
  const float* xrowBase = x + (size_t)arow*S_*D_;
  const bool writer = (layer == 1);

  bool dead = false;

  for (int t = 0; t < S_; ++t) {
    half8 ain[8], arec[8];

    if (layer == 0) {
      // x loads issued BEFORE the flag wait (independent of recurrence)
      const float* xr = xrowBase + (size_t)t*D_;
#pragma unroll
      for (int kk = 0; kk < 8; ++kk) {
        const int k = kk*32 + quad*8;
        half8 hv;
        if (dir == 0) {
          f32x4 a0 = *(const f32x4*)(xr + k);
          f32x4 a1 = *(const f32x4*)(xr + k + 4);
          hv[0]=(_Float16)a0[0]; hv[1]=(_Float16)a0[1]; hv[2]=(_Float16)a0[2]; hv[3]=(_Float16)a0[3];
          hv[4]=(_Float16)a1[0]; hv[5]=(_Float16)a1[1]; hv[6]=(_Float16)a1[2]; hv[7]=(_Float16)a1[3];
        } else {
          // feature-reversed: u[k+j] = x[255-k-j] = p[7-j], p = xr + 248 - k
          const float* p = xr + (248 - k);
          f32x4 a0 = *(const f32x4*)p;
          f32x4 a1 = *(const f32x4*)(p + 4);
          hv[0]=(_Float16)a1[3]; hv[1]=(_Float16)a1[2]; hv[2]=(_Float16)a1[1]; hv[3]=(_Float16)a1[0];
          hv[4]=(_Float16)a0[3]; hv[5]=(_Float16)a0[2]; hv[6]=(_Float16)a0[1]; hv[7]=(_Float16)a0[0];
        }
        ain[kk] = hv;
      }
    }

    // ---- spin: flags via FAST(L2) or SYS(IF$); data always SYS ----
    {
      const int tgt = t + tgtOff;
      int guard = 0;
      while (true) {
        int v = flag_poll<FFAST>(spinPtr);
        if (__all(v >= tgt)) break;
        if (++guard > (1 << 20)) { dead = true; break; }
      }
    }
    if (dead) break;
    asm volatile("" ::: "memory");   // pin data loads after the spin

    if (layer == 0) {
      const _Float16* hs = hbufOwn + (size_t)(t & 7)*HB_SLOT + (size_t)lq*H_ + quad*8;
#pragma unroll
      for (int kk = 0; kk < 8; ++kk)
        arec[kk] = ld_h8_sys(hs + kk*32);
    } else {
      const _Float16* hi = hbufL0 + (size_t)((t+1) & 7)*HB_SLOT + (size_t)lq*H_ + quad*8;
      const _Float16* hr = hbufOwn + (size_t)(t & 7)*HB_SLOT + (size_t)lq*H_ + quad*8;
#pragma unroll
      for (int kk = 0; kk < 8; ++kk) {
        ain[kk]  = ld_h8_sys(hi + kk*32);
        arec[kk] = ld_h8_sys(hr + kk*32);
      }
    }

    f32x4 acc0 = {bias[0],bias[0],bias[0],bias[0]};
    f32x4 acc1 = {bias[1],bias[1],bias[1],bias[1]};
    f32x4 acc2 = {bias[2],bias[2],bias[2],bias[2]};
    f32x4 acc3 = {bias[3],bias[3],bias[3],bias[3]};
#pragma unroll
    for (int kk = 0; kk < 8; ++kk) {
      acc0 = __builtin_amdgcn_mfma_f32_16x16x32_f16(ain[kk], bf[0][kk], acc0, 0,0,0);
      acc1 = __builtin_amdgcn_mfma_f32_16x16x32_f16(ain[kk], bf[1][kk], acc1, 0,0,0);
      acc2 = __builtin_amdgcn_mfma_f32_16x16x32_f16(ain[kk], bf[2][kk], acc2, 0,0,0);
      acc3 = __builtin_amdgcn_mfma_f32_16x16x32_f16(ain[kk], bf[3][kk], acc3, 0,0,0);
    }
#pragma unroll
    for (int kk = 0; kk < 8; ++kk) {
      acc0 = __builtin_amdgcn_mfma_f32_16x16x32_f16(arec[kk], bf[0][kk+8], acc0, 0,0,0);
      acc1 = __builtin_amdgcn_mfma_f32_16x16x32_f16(arec[kk], bf[1][kk+8], acc1, 0,0,0);
      acc2 = __builtin_amdgcn_mfma_f32_16x16x32_f16(arec[kk], bf[2][kk+8], acc2, 0,0,0);
      acc3 = __builtin_amdgcn_mfma_f32_16x16x32_f16(arec[kk], bf[3][kk+8], acc3, 0,0,0);
    }

    // LSTM elementwise, fully in-register
    float hval[4];
#pragma unroll
    for (int r = 0; r < 4; ++r) {
      float si = sigmoidf_(acc0[r]);
      float sf = sigmoidf_(acc1[r]);
      float tg = tanhf_  (acc2[r]);
      float so = sigmoidf_(acc3[r]);
      float cn = sf*cst[r] + si*tg;
      cst[r] = cn;
      hval[r] = so*tanhf_(cn);
    }

    // publish h(t) slice (f16) to slot (t+1)&7 — SYSTEM scope (R2-proven),
    // dword-packed via shfl_xor
    _Float16* hw = hbufOwn + (size_t)((t+1) & 7)*HB_SLOT + c0 + lq;
#pragma unroll
    for (int r = 0; r < 4; ++r) {
      float partner = __shfl_xor(hval[r], 1);
      if (!(lq & 1)) {
        unsigned short lo = __builtin_bit_cast(unsigned short, (_Float16)hval[r]);
        unsigned short hi = __builtin_bit_cast(unsigned short, (_Float16)partner);
        unsigned u = (unsigned)lo | ((unsigned)hi << 16);
        const int bl = quad*4 + r;   // local row within the 16-row half
        __hip_atomic_store((unsigned*)(hw + (size_t)bl*H_), u,
                           __ATOMIC_RELAXED, __HIP_MEMORY_SCOPE_SYSTEM);
      }
    }
    // drain publish stores to the IF$ (R2-proven ack), then raise the flag
    // (flag itself goes through the XCD L2 when FAST).
    asm volatile("s_waitcnt vmcnt(0)" ::: "memory");
    if (lane == 0)
      flag_raise<FFAST>(myFlag, t+1);

    // out[] stores AFTER the flag publish — off the critical path
    if (writer) {
      const int colg = dir*256 + c0 + lq;
#pragma unroll
      for (int r = 0; r < 4; ++r) {
        const int b = m*16 + quad*4 + r;
        out[((size_t)b*S_ + t)*(2*H_) + colg] = hval[r];
      }
      if (t == S_-1) {
#pragma unroll
        for (int r = 0; r < 4; ++r) {
          const int b = m*16 + quad*4 + r;
          out[OUT0 + (size_t)b*(2*H_) + colg] = hval[r];          // h_last
          out[OUT0 + B_*2*H_ + (size_t)b*(2*H_) + colg] = cst[r]; // c_last
        }
      }
    }
  }
}

__global__ __launch_bounds__(64,1) void lstm_main(
    const float* __restrict__ x,
    const float* __restrict__ enc_c,
    const float* __restrict__ Wih_f, const float* __restrict__ Whh_f,
    const float* __restrict__ bih_f, const float* __restrict__ bhh_f,
    const float* __restrict__ Wih_b, const float* __restrict__ Whh_b,
    const float* __restrict__ bih_b, const float* __restrict__ bhh_b,
    float* __restrict__ out,
    int* __restrict__ flags,
    int* __restrict__ cnt,
    int* __restrict__ epoch,
    int* __restrict__ toks,
    int* __restrict__ verd,
    _Float16* __restrict__ hbuf)
{
  // ---- ground-truth co-residency: claim a slot on THIS block's own XCD ----
  unsigned xcc;
  asm volatile("s_getreg_b32 %0, hwreg(HW_REG_XCC_ID)" : "=s"(xcc));
  xcc &= 7;
  if (xcc >= 4) return;                 // regions live on XCDs 0..3
  const int region = (int)xcc;          // region = (dir<<1)|m
  const int lane = threadIdx.x;

  int tk = 0;
  if (lane == 0)
    tk = __hip_atomic_fetch_add(cnt + region, 1, __ATOMIC_RELAXED,
                                __HIP_MEMORY_SCOPE_SYSTEM);
  tk = __shfl(tk, 0);
  if (tk >= 32) return;                 // region full
  const int member = tk;                // layer = member&1, colgrp = member>>1

  const unsigned E = (unsigned)__hip_atomic_load(epoch, __ATOMIC_RELAXED,
                                                 __HIP_MEMORY_SCOPE_SYSTEM);

  // ---- two-generation, epoch-keyed probe of sc0/L2 flag visibility -------
  int* tokR = toks + region*32;
  bool ok = true;
#pragma unroll 1
  for (int phase = 1; phase <= 2; ++phase) {
    const unsigned tgt = E*2u + (unsigned)phase;
    if (lane == 0) st_dw_fast((unsigned*)&tokR[member], tgt);
    int guard = 0;
    while (true) {
      int v = ld_flag_fast(&tokR[lane & 31]);
      if (__all((int)((unsigned)v - tgt) >= 0)) break;
      if (++guard > (1 << 17)) { ok = false; break; }
    }
    if (!ok) break;
  }

  // ---- verdict agreement (system scope; always coherent) ------------------
  if (lane == 0)
    __hip_atomic_store(&verd[region*32 + member], ok ? 1 : 0,
                       __ATOMIC_RELAXED, __HIP_MEMORY_SCOPE_SYSTEM);
  int vd = -1; bool have = true;
  {
    int guard = 0;
    while (true) {
      vd = __hip_atomic_load(&verd[region*32 + (lane & 31)],
                             __ATOMIC_RELAXED, __HIP_MEMORY_SCOPE_SYSTEM);
      if (__all(vd >= 0)) break;
      if (++guard > (1 << 18)) { have = false; break; }
    }
  }
  const bool fast = have && __all(vd == 1);

  const int dir = region >> 1;
  const float* Wih = dir ? Wih_b : Wih_f;
  const float* Whh = dir ? Whh_b : Whh_f;
  const float* bih = dir ? bih_b : bih_f;
  const float* bhh = dir ? bhh_b : bhh_f;

  if (fast)
    run_lstm<true >(x, enc_c, Wih, Whh, bih, bhh, out, flags, hbuf, region, member);
  else
    run_lstm<false>(x, enc_c, Wih, Whh, bih, bhh, out, flags, hbuf, region, member);
}

extern "C" void kernel_launch(void* const* d_in, const int* in_sizes, int n_in,
                              void* d_out, int out_size, void* d_ws, size_t ws_size,
                              hipStream_t stream) {
  const float* x     = (const float*)d_in[0];
  const float* enc_h = (const float*)d_in[1];
  const float* enc_c = (const float*)d_in[2];
  const float* Wih_f = (const float*)d_in[3];
  const float* Whh_f = (const float*)d_in[4];
  const float* bih_f = (const float*)d_in[5];
  const float* bhh_f = (const float*)d_in[6];
  const float* Wih_b = (const float*)d_in[7];
  const float* Whh_b = (const float*)d_in[8];
  const float* bih_b = (const float*)d_in[9];
  const float* bhh_b = (const float*)d_in[10];

  int* flags     = (int*)d_ws;                          // 8 KB
  int* cnt       = (int*)((char*)d_ws + 8192);          // 8 ints
  int* epoch     = (int*)((char*)d_ws + 8448);          // 1 int (persistent)
  int* toks      = (int*)((char*)d_ws + 8704);          // 128 ints
  int* verd      = (int*)((char*)d_ws + 9728);          // 128 ints
  _Float16* hbuf = (_Float16*)((char*)d_ws + 32768);    // 512 KB

  lstm_prep<<<64, 256, 0, stream>>>(enc_h, flags, cnt, epoch, toks, verd, hbuf);
  lstm_main<<<512, 64, 0, stream>>>(x, enc_c, Wih_f, Whh_f, bih_f, bhh_f,
                                    Wih_b, Whh_b, bih_b, bhh_b,
                                    (float*)d_out, flags, cnt, epoch, toks, verd, hbuf);
}

// Round 3
// 18855.473 us; speedup vs baseline: 1.4035x; 1.4035x over previous
//
#include <hip/hip_runtime.h>

// R5: row-partitioned quarter topology, all system-scope (R2-proven primitives).
//
// 32 blocks = dir(2) x layer(2) x m(2) x quarter(4); each block = 4 waves
// (256 thr, 1 wave/SIMD -> always launchable). Wave wv owns h-cols
// Q*64 + wv*16 .. +15 with its 64KB weight slice resident in registers
// (same per-wave resource profile as R2). The LSTM recurrence is per-row,
// so a block's 16 rows never leave it; the only cross-block traffic is the
// h-column gather from the 3 same-layer quarter partners (+ the pipelined
// L0->L1 handoff). Poll fan-in drops 16 -> 7, flag publishers 128 -> 32
// (one per block, after a barrier-collected vmcnt(0) drain). Protocol and
// primitives are byte-identical to R2 (relaxed SYSTEM atomics, sc0 sc1,
// IF$-coherent): placement-independent correctness.

typedef _Float16 half8 __attribute__((ext_vector_type(8)));
typedef float f32x4 __attribute__((ext_vector_type(4)));

#define B_ 32
#define S_ 2048
#define D_ 256
#define H_ 256
#define G_ 1024
#define NSLOT 8
#define OUT0 (B_*S_*2*H_)   /* 33554432 */

// per-block hbuf: NSLOT slots x [16 rows][64 cols] f16
#define SLOT_F16 (16*64)            /* 1024 f16 = 2KB  */
#define BLK_F16  (NSLOT*SLOT_F16)   /* 8192 f16 = 16KB */

__device__ __forceinline__ float sigmoidf_(float v){ return 1.f/(1.f+__expf(-v)); }
__device__ __forceinline__ float tanhf_(float v){ return 2.f/(1.f+__expf(-2.f*v)) - 1.f; }

union H8U { half8 h; unsigned u[4]; };

// R2-proven system-scope 16B coherent load (4 relaxed system atomics; the
// compiler inserts the vmcnt waits before use).
__device__ __forceinline__ half8 ld_h8_sys(const _Float16* p) {
  const unsigned* u = (const unsigned*)p;
  H8U r;
  r.u[0] = __hip_atomic_load(u+0, __ATOMIC_RELAXED, __HIP_MEMORY_SCOPE_SYSTEM);
  r.u[1] = __hip_atomic_load(u+1, __ATOMIC_RELAXED, __HIP_MEMORY_SCOPE_SYSTEM);
  r.u[2] = __hip_atomic_load(u+2, __ATOMIC_RELAXED, __HIP_MEMORY_SCOPE_SYSTEM);
  r.u[3] = __hip_atomic_load(u+3, __ATOMIC_RELAXED, __HIP_MEMORY_SCOPE_SYSTEM);
  return r.h;
}

// ws layout: [0, 2K): flags (32 blocks, 64B stride)
//            [32K, 32K+512K): hbuf (32 blocks x 16KB)
__global__ __launch_bounds__(256) void lstm_prep(const float* __restrict__ enc_h,
                                                 int* __restrict__ flags,
                                                 _Float16* __restrict__ hbuf)
{
  int idx = blockIdx.x*blockDim.x + threadIdx.x;
  if (idx < 32)
    __hip_atomic_store(&flags[idx*16], 0, __ATOMIC_RELAXED, __HIP_MEMORY_SCOPE_SYSTEM);
  // gen-0 init: slot 0 of every block (32 x 16 x 64 f16 = 16384 dwords)
  for (int j = idx; j < 32*16*32; j += gridDim.x*blockDim.x) {
    int c2  = j & 31;            // col pair 0..31
    int row = (j >> 5) & 15;
    int blk = j >> 9;            // 0..31
    int Q   = blk & 3;
    int m   = (blk >> 2) & 1;
    int dir = blk >> 4;          // layer doesn't affect the init value
    int b    = m*16 + row;
    int gcol = Q*64 + c2*2;
    _Float16 lo = (_Float16)enc_h[b*(2*H_) + dir*H_ + gcol];
    _Float16 hi = (_Float16)enc_h[b*(2*H_) + dir*H_ + gcol + 1];
    unsigned u = (unsigned)__builtin_bit_cast(unsigned short, lo)
               | ((unsigned)__builtin_bit_cast(unsigned short, hi) << 16);
    __hip_atomic_store((unsigned*)(hbuf + (size_t)blk*BLK_F16 + row*64 + c2*2), u,
                       __ATOMIC_RELAXED, __HIP_MEMORY_SCOPE_SYSTEM);
  }
}

__global__ __launch_bounds__(256,1) void lstm_main(
    const float* __restrict__ x,
    const float* __restrict__ enc_c,
    const float* __restrict__ Wih_f, const float* __restrict__ Whh_f,
    const float* __restrict__ bih_f, const float* __restrict__ bhh_f,
    const float* __restrict__ Wih_b, const float* __restrict__ Whh_b,
    const float* __restrict__ bih_b, const float* __restrict__ bhh_b,
    float* __restrict__ out,
    int* __restrict__ flags,
    _Float16* __restrict__ hbuf)
{
  const int blk   = blockIdx.x;      // 0..31
  const int Q     = blk & 3;
  const int m     = (blk >> 2) & 1;
  const int layer = (blk >> 3) & 1;
  const int dir   = blk >> 4;
  const int tid   = threadIdx.x;
  const int wv    = tid >> 6;        // wave 0..3
  const int lane  = tid & 63;
  const int quad  = lane >> 4;
  const int lq    = lane & 15;

  const float* Wih = dir ? Wih_b : Wih_f;
  const float* Whh = dir ? Whh_b : Whh_f;
  const float* bih = dir ? bih_b : bih_f;
  const float* bhh = dir ? bhh_b : bhh_f;

  const int gbase = Q*64 + wv*16;    // this wave's h-col base (16 cols)

  // ---- resident B-fragments: bf[q][kk], q=gate(i,f,g,o), kk=K-frag ----
  // B[k][n]: lane -> n = q*256 + gbase + lq, k = kk*32 + quad*8 + j
  half8 bf[4][16];
#pragma unroll
  for (int q = 0; q < 4; ++q) {
    const int n_g = q*256 + gbase + lq;
    const float* wihr = Wih + (size_t)layer*G_*256 + (size_t)n_g*256 + quad*8;
    const float* whhr = Whh + (size_t)layer*G_*256 + (size_t)n_g*256 + quad*8;
#pragma unroll
    for (int kk = 0; kk < 16; ++kk) {
      const float* src = (kk < 8) ? (wihr + kk*32) : (whhr + (kk-8)*32);
      f32x4 w0 = *(const f32x4*)src;
      f32x4 w1 = *(const f32x4*)(src+4);
      half8 hv;
      hv[0]=(_Float16)w0[0]; hv[1]=(_Float16)w0[1]; hv[2]=(_Float16)w0[2]; hv[3]=(_Float16)w0[3];
      hv[4]=(_Float16)w1[0]; hv[5]=(_Float16)w1[1]; hv[6]=(_Float16)w1[2]; hv[7]=(_Float16)w1[3];
      bf[q][kk] = hv;
    }
  }

  float bias[4];
#pragma unroll
  for (int q = 0; q < 4; ++q) {
    const int n_g = q*256 + gbase + lq;
    bias[q] = bih[layer*G_ + n_g] + bhh[layer*G_ + n_g];
  }

  // c-state in C/D layout: row = m*16 + quad*4 + r, col = gbase + lq
  f32x4 cst;
#pragma unroll
  for (int r = 0; r < 4; ++r) {
    const int b = m*16 + quad*4 + r;
    cst[r] = enc_c[b*(2*H_) + dir*H_ + gbase + lq];
  }

  const int sameBase  = (dir<<4) | (layer<<3) | (m<<2);  // + quarter
  const int otherBase = sameBase ^ 8;
  _Float16* ownBlk = hbuf + (size_t)blk*BLK_F16;
  int* myFlag = flags + blk*16;

  // per-lane spin assignment (7 real flags, rest replicate lane 0):
  //  lanes 0..2: same-layer quarter partners, tgt = t
  //  lanes 3..6: other-layer quarters, tgt = t + (layer ? +1 : -7)
  int fblk, tgtOff;
  if (lane < 3)      { fblk = sameBase  + ((Q + 1 + lane) & 3); tgtOff = 0; }
  else if (lane < 7) { fblk = otherBase + (lane - 3); tgtOff = layer ? 1 : -7; }
  else               { fblk = sameBase  + ((Q + 1) & 3); tgtOff = 0; }
  const int* spinPtr = flags + fblk*16;

  __shared__ int ldsDead;
  if (tid == 0) ldsDead = 0;
  __syncthreads();

  const int arow = m*16 + lq;              // global batch row this lane feeds
  const float* xrowBase = x + (size_t)arow*S_*D_;

  for (int t = 0; t < S_; ++t) {
    half8 ain[8], arec[8];

    if (layer == 0) {
      // x loads issued BEFORE the flag wait (independent of recurrence)
      const float* xr = xrowBase + (size_t)t*D_;
#pragma unroll
      for (int kk = 0; kk < 8; ++kk) {
        const int k = kk*32 + quad*8;
        half8 hv;
        if (dir == 0) {
          f32x4 a0 = *(const f32x4*)(xr + k);
          f32x4 a1 = *(const f32x4*)(xr + k + 4);
          hv[0]=(_Float16)a0[0]; hv[1]=(_Float16)a0[1]; hv[2]=(_Float16)a0[2]; hv[3]=(_Float16)a0[3];
          hv[4]=(_Float16)a1[0]; hv[5]=(_Float16)a1[1]; hv[6]=(_Float16)a1[2]; hv[7]=(_Float16)a1[3];
        } else {
          // feature-reversed: u[k+j] = x[255-k-j] = p[7-j], p = xr + 248 - k
          const float* p = xr + (248 - k);
          f32x4 a0 = *(const f32x4*)p;
          f32x4 a1 = *(const f32x4*)(p + 4);
          hv[0]=(_Float16)a1[3]; hv[1]=(_Float16)a1[2]; hv[2]=(_Float16)a1[1]; hv[3]=(_Float16)a1[0];
          hv[4]=(_Float16)a0[3]; hv[5]=(_Float16)a0[2]; hv[6]=(_Float16)a0[1]; hv[7]=(_Float16)a0[0];
        }
        ain[kk] = hv;
      }
    }

    // ---- spin (relaxed SYSTEM polls, R2-proven) ----
    {
      const int tgt = t + tgtOff;
      int guard = 0;
      while (true) {
        int v = __hip_atomic_load(spinPtr, __ATOMIC_RELAXED, __HIP_MEMORY_SCOPE_SYSTEM);
        if (__all(v >= tgt)) break;
        if (++guard > (1 << 18)) { ldsDead = 1; break; }  // uniform exit via barrier below
      }
    }
    asm volatile("" ::: "memory");   // pin data loads after the spin

    // arec: own-layer h(t) gen from the 4 quarter slots (own quarter's stores
    // were drained before last tick's barrier -> no flag needed for self)
#pragma unroll
    for (int kk = 0; kk < 8; ++kk) {
      const int qq = kk >> 1;        // quarter holding K = kk*32..kk*32+31
      const _Float16* p = hbuf + (size_t)(sameBase + qq)*BLK_F16
                        + (size_t)(t & 7)*SLOT_F16
                        + (size_t)lq*64 + (kk & 1)*32 + quad*8;
      arec[kk] = ld_h8_sys(p);
    }
    if (layer == 1) {
#pragma unroll
      for (int kk = 0; kk < 8; ++kk) {
        const int qq = kk >> 1;
        const _Float16* p = hbuf + (size_t)(otherBase + qq)*BLK_F16
                          + (size_t)((t+1) & 7)*SLOT_F16
                          + (size_t)lq*64 + (kk & 1)*32 + quad*8;
        ain[kk] = ld_h8_sys(p);
      }
    }

    f32x4 acc0 = {bias[0],bias[0],bias[0],bias[0]};
    f32x4 acc1 = {bias[1],bias[1],bias[1],bias[1]};
    f32x4 acc2 = {bias[2],bias[2],bias[2],bias[2]};
    f32x4 acc3 = {bias[3],bias[3],bias[3],bias[3]};
#pragma unroll
    for (int kk = 0; kk < 8; ++kk) {
      acc0 = __builtin_amdgcn_mfma_f32_16x16x32_f16(ain[kk], bf[0][kk], acc0, 0,0,0);
      acc1 = __builtin_amdgcn_mfma_f32_16x16x32_f16(ain[kk], bf[1][kk], acc1, 0,0,0);
      acc2 = __builtin_amdgcn_mfma_f32_16x16x32_f16(ain[kk], bf[2][kk], acc2, 0,0,0);
      acc3 = __builtin_amdgcn_mfma_f32_16x16x32_f16(ain[kk], bf[3][kk], acc3, 0,0,0);
    }
#pragma unroll
    for (int kk = 0; kk < 8; ++kk) {
      acc0 = __builtin_amdgcn_mfma_f32_16x16x32_f16(arec[kk], bf[0][kk+8], acc0, 0,0,0);
      acc1 = __builtin_amdgcn_mfma_f32_16x16x32_f16(arec[kk], bf[1][kk+8], acc1, 0,0,0);
      acc2 = __builtin_amdgcn_mfma_f32_16x16x32_f16(arec[kk], bf[2][kk+8], acc2, 0,0,0);
      acc3 = __builtin_amdgcn_mfma_f32_16x16x32_f16(arec[kk], bf[3][kk+8], acc3, 0,0,0);
    }

    // LSTM elementwise, fully in-register
    float hval[4];
#pragma unroll
    for (int r = 0; r < 4; ++r) {
      float si = sigmoidf_(acc0[r]);
      float sf = sigmoidf_(acc1[r]);
      float tg = tanhf_  (acc2[r]);
      float so = sigmoidf_(acc3[r]);
      float cn = sf*cst[r] + si*tg;
      cst[r] = cn;
      hval[r] = so*tanhf_(cn);
    }

    // publish h(t+1) slice to own slot (t+1)&7; dword-packed via shfl_xor
    _Float16* hw = ownBlk + (size_t)((t+1) & 7)*SLOT_F16 + wv*16 + lq;
#pragma unroll
    for (int r = 0; r < 4; ++r) {
      float partner = __shfl_xor(hval[r], 1);
      if (!(lq & 1)) {
        unsigned short lo = __builtin_bit_cast(unsigned short, (_Float16)hval[r]);
        unsigned short hi = __builtin_bit_cast(unsigned short, (_Float16)partner);
        unsigned u = (unsigned)lo | ((unsigned)hi << 16);
        const int bl = quad*4 + r;   // local row 0..15
        __hip_atomic_store((unsigned*)(hw + (size_t)bl*64), u,
                           __ATOMIC_RELAXED, __HIP_MEMORY_SCOPE_SYSTEM);
      }
    }
    // drain all publish stores to the coherence point, sync the block, then
    // raise the single block flag.
    asm volatile("s_waitcnt vmcnt(0)" ::: "memory");
    __syncthreads();
    if (tid == 0)
      __hip_atomic_store(myFlag, t+1, __ATOMIC_RELAXED, __HIP_MEMORY_SCOPE_SYSTEM);

    // out[] stores AFTER the flag publish — off the critical path
    if (layer == 1) {
      const int colg = dir*256 + gbase + lq;
#pragma unroll
      for (int r = 0; r < 4; ++r) {
        const int b = m*16 + quad*4 + r;
        out[((size_t)b*S_ + t)*(2*H_) + colg] = hval[r];
      }
      if (t == S_-1) {
#pragma unroll
        for (int r = 0; r < 4; ++r) {
          const int b = m*16 + quad*4 + r;
          out[OUT0 + (size_t)b*(2*H_) + colg] = hval[r];          // h_last
          out[OUT0 + B_*2*H_ + (size_t)b*(2*H_) + colg] = cst[r]; // c_last
        }
      }
    }

    if (ldsDead) break;   // read after barrier: uniform across the block
  }
}

extern "C" void kernel_launch(void* const* d_in, const int* in_sizes, int n_in,
                              void* d_out, int out_size, void* d_ws, size_t ws_size,
                              hipStream_t stream) {
  const float* x     = (const float*)d_in[0];
  const float* enc_h = (const float*)d_in[1];
  const float* enc_c = (const float*)d_in[2];
  const float* Wih_f = (const float*)d_in[3];
  const float* Whh_f = (const float*)d_in[4];
  const float* bih_f = (const float*)d_in[5];
  const float* bhh_f = (const float*)d_in[6];
  const float* Wih_b = (const float*)d_in[7];
  const float* Whh_b = (const float*)d_in[8];
  const float* bih_b = (const float*)d_in[9];
  const float* bhh_b = (const float*)d_in[10];

  int* flags     = (int*)d_ws;                          // 2 KB used
  _Float16* hbuf = (_Float16*)((char*)d_ws + 32768);    // 512 KB

  lstm_prep<<<64, 256, 0, stream>>>(enc_h, flags, hbuf);
  lstm_main<<<32, 256, 0, stream>>>(x, enc_c, Wih_f, Whh_f, bih_f, bhh_f,
                                    Wih_b, Whh_b, bih_b, bhh_b,
                                    (float*)d_out, flags, hbuf);
}

// Round 4
// 14099.481 us; speedup vs baseline: 1.8769x; 1.3373x over previous
//
#include <hip/hip_runtime.h>

// R6: flagless tag-in-data protocol (R2 topology: 128 one-wave blocks).
//
// R2's tick had 4 serial IF$ legs: publish -> vmcnt(0) ack -> flag store ->
// flag-poll detect -> separate h load. R6 merges flag+data: h published as
// 8B packets [h_f16, h_f16, tag32] via one global_store_dwordx2 (sc0 sc1,
// relaxed SYSTEM atomic). tag = epoch*4096 + generation; epoch bumps every
// launch, so stale workspace / graph replay can never alias a tag. The
// consumer probes one packet per producer (tag==gen), then bulk-loads all
// packets and verifies every tag (retry on partial arrival) — the verified
// iteration IS the data. Producer: fire-and-forget (no drain, no flag).
//
// Slot safety (ring of NSLOT=4 generations):
//  - intra-layer drift <=1 (enforced by the all-gather itself), ring>=2 ok.
//  - L0 overwrites h0 gen t-3 with gen t+1 only after its backpressure probe
//    shows L1 tags >= gen t-3  =>  all L1 finished step t-4  =>  consumed
//    h0 gen t-3. L1 consuming h0 gen t+1 can't be overwritten: that would
//    need L0 at step t+4 => bp >= gen t+1 => this L1 finished step t. QED.

typedef _Float16 half8 __attribute__((ext_vector_type(8)));
typedef float f32x4 __attribute__((ext_vector_type(4)));
typedef unsigned u32x4v __attribute__((ext_vector_type(4)));
typedef unsigned long long ull;

#define B_ 32
#define S_ 2048
#define D_ 256
#define H_ 256
#define G_ 1024
#define OUT0 (B_*S_*2*H_)   /* 33554432 */

#define NSLOT 4
#define PKTROW 128          /* packets per row = 256 cols / 2 */

__device__ __forceinline__ size_t hoff(int chain, int slot, int row, int pkt){
  return ((size_t)((chain*NSLOT + slot)*B_ + row))*PKTROW + pkt;
}

__device__ __forceinline__ float sigmoidf_(float v){ return 1.f/(1.f+__expf(-v)); }
__device__ __forceinline__ float tanhf_(float v){ return 2.f/(1.f+__expf(-2.f*v)) - 1.f; }

__device__ __forceinline__ ull ld_pkt(const ull* p){
  return __hip_atomic_load(p, __ATOMIC_RELAXED, __HIP_MEMORY_SCOPE_SYSTEM);
}
__device__ __forceinline__ void st_pkt(ull* p, ull v){
  __hip_atomic_store(p, v, __ATOMIC_RELAXED, __HIP_MEMORY_SCOPE_SYSTEM);
}

// ---------------------------------------------------------------------------
__global__ __launch_bounds__(64) void epoch_bump(unsigned* __restrict__ epoch)
{
  if (threadIdx.x == 0)
    __hip_atomic_fetch_add(epoch, 1u, __ATOMIC_RELAXED, __HIP_MEMORY_SCOPE_SYSTEM);
}

// gen-0 init: slot 0 of all 4 (dir,layer) buffers, tag = E*4096.
__global__ __launch_bounds__(256) void lstm_prep(const float* __restrict__ enc_h,
                                                 const unsigned* __restrict__ epoch,
                                                 ull* __restrict__ hb)
{
  const unsigned tag0 = __hip_atomic_load(epoch, __ATOMIC_RELAXED,
                                          __HIP_MEMORY_SCOPE_SYSTEM) * 4096u;
  int idx = blockIdx.x*blockDim.x + threadIdx.x;
  for (int j = idx; j < 4*B_*PKTROW; j += gridDim.x*blockDim.x) {
    int pkt   = j & 127;
    int row   = (j >> 7) & 31;
    int chain = j >> 12;            // 32*128 = 4096 = 2^12
    int dirv  = chain >> 1;         // layer does not affect the init value
    int col   = pkt*2;
    _Float16 lo = (_Float16)enc_h[row*(2*H_) + dirv*H_ + col];
    _Float16 hi = (_Float16)enc_h[row*(2*H_) + dirv*H_ + col + 1];
    unsigned pair = (unsigned)__builtin_bit_cast(unsigned short, lo)
                  | ((unsigned)__builtin_bit_cast(unsigned short, hi) << 16);
    st_pkt(hb + hoff(chain, 0, row, pkt), ((ull)tag0 << 32) | pair);
  }
}

// ---------------------------------------------------------------------------
__global__ __launch_bounds__(64,1) void lstm_main(
    const float* __restrict__ x,
    const float* __restrict__ enc_c,
    const float* __restrict__ Wih_f, const float* __restrict__ Whh_f,
    const float* __restrict__ bih_f, const float* __restrict__ bhh_f,
    const float* __restrict__ Wih_b, const float* __restrict__ Whh_b,
    const float* __restrict__ bih_b, const float* __restrict__ bhh_b,
    float* __restrict__ out,
    const unsigned* __restrict__ epoch,
    ull* __restrict__ hb)
{
  const int bid   = blockIdx.x;   // 0..127
  const int chain = bid & 3;      // dir*2 + layer
  const int w     = bid >> 2;     // member 0..31
  const int dir   = chain >> 1;
  const int layer = chain & 1;
  const int m     = w & 1;        // batch 16-row half
  const int c0    = (w >> 1) << 4;// h-column base (16 cols)
  const int lane  = threadIdx.x;  // 64
  const int quad  = lane >> 4;
  const int lq    = lane & 15;

  const float* Wih = dir ? Wih_b : Wih_f;
  const float* Whh = dir ? Whh_b : Whh_f;
  const float* bih = dir ? bih_b : bih_f;
  const float* bhh = dir ? bhh_b : bhh_f;

  // ---- resident B-fragments: bf[q][kk], q=gate(i,f,g,o), kk=K-frag ----
  half8 bf[4][16];
#pragma unroll
  for (int q = 0; q < 4; ++q) {
    const int n_g = q*256 + c0 + lq;
    const float* wihr = Wih + (size_t)layer*G_*256 + (size_t)n_g*256 + quad*8;
    const float* whhr = Whh + (size_t)layer*G_*256 + (size_t)n_g*256 + quad*8;
#pragma unroll
    for (int kk = 0; kk < 16; ++kk) {
      const float* src = (kk < 8) ? (wihr + kk*32) : (whhr + (kk-8)*32);
      f32x4 w0 = *(const f32x4*)src;
      f32x4 w1 = *(const f32x4*)(src+4);
      half8 hv;
      hv[0]=(_Float16)w0[0]; hv[1]=(_Float16)w0[1]; hv[2]=(_Float16)w0[2]; hv[3]=(_Float16)w0[3];
      hv[4]=(_Float16)w1[0]; hv[5]=(_Float16)w1[1]; hv[6]=(_Float16)w1[2]; hv[7]=(_Float16)w1[3];
      bf[q][kk] = hv;
    }
  }

  float bias[4];
#pragma unroll
  for (int q = 0; q < 4; ++q) {
    const int n_g = q*256 + c0 + lq;
    bias[q] = bih[layer*G_ + n_g] + bhh[layer*G_ + n_g];
  }

  // c-state in C/D layout: row = m*16 + quad*4 + r, col = c0+lq
  f32x4 cst;
#pragma unroll
  for (int r = 0; r < 4; ++r) {
    const int b = m*16 + quad*4 + r;
    cst[r] = enc_c[b*(2*H_) + dir*H_ + c0 + lq];
  }

  const unsigned EB = __hip_atomic_load(epoch, __ATOMIC_RELAXED,
                                        __HIP_MEMORY_SCOPE_SYSTEM) * 4096u;

  // probe geometry: lanes (0-15,32-47) probe own-layer members (tag==gen t);
  // lanes (16-31,48-63): L0 -> backpressure on L1 (tag >= gen t-3),
  //                      L1 -> upstream L0 (tag == gen t+1).
  const int  pm        = lane & 15;          // probed member
  const int  probeRow  = m*16 + 15;
  const int  probePkt  = pm*8 + 7;           // that member's last-written packet
  const bool probeAlt  = ((lane >> 4) & 1) != 0;   // bp (L0) / upstream (L1)

  const int arow = m*16 + lq;                // batch row this lane feeds
  const float* xrowBase = x + (size_t)arow*S_*D_;

  bool dead = false;

  for (int t = 0; t < S_; ++t) {
    half8 ain[8], arec[8];
    const unsigned tagT = EB + (unsigned)t;

    if (layer == 0) {
      // x loads issued BEFORE the wait (independent of recurrence)
      const float* xr = xrowBase + (size_t)t*D_;
#pragma unroll
      for (int kk = 0; kk < 8; ++kk) {
        const int k = kk*32 + quad*8;
        half8 hv;
        if (dir == 0) {
          f32x4 a0 = *(const f32x4*)(xr + k);
          f32x4 a1 = *(const f32x4*)(xr + k + 4);
          hv[0]=(_Float16)a0[0]; hv[1]=(_Float16)a0[1]; hv[2]=(_Float16)a0[2]; hv[3]=(_Float16)a0[3];
          hv[4]=(_Float16)a1[0]; hv[5]=(_Float16)a1[1]; hv[6]=(_Float16)a1[2]; hv[7]=(_Float16)a1[3];
        } else {
          // feature-reversed: u[k+j] = x[255-k-j] = p[7-j], p = xr + 248 - k
          const float* p = xr + (248 - k);
          f32x4 a0 = *(const f32x4*)p;
          f32x4 a1 = *(const f32x4*)(p + 4);
          hv[0]=(_Float16)a1[3]; hv[1]=(_Float16)a1[2]; hv[2]=(_Float16)a1[1]; hv[3]=(_Float16)a1[0];
          hv[4]=(_Float16)a0[3]; hv[5]=(_Float16)a0[2]; hv[6]=(_Float16)a0[1]; hv[7]=(_Float16)a0[0];
        }
        ain[kk] = hv;
      }
    }

    // ---- phase A: probe detect (one packet tag per producer) ----
    {
      const ull* pp;
      unsigned want;
      bool isGE = false;
      if (layer == 0) {
        if (!probeAlt) { pp = hb + hoff(chain,   t&3,     probeRow, probePkt); want = tagT; }
        else           { pp = hb + hoff(chain+1, (t+1)&3, probeRow, probePkt); want = tagT - 3; isGE = true; }
      } else {
        if (!probeAlt) { pp = hb + hoff(chain,   t&3,     probeRow, probePkt); want = tagT; }
        else           { pp = hb + hoff(chain-1, (t+1)&3, probeRow, probePkt); want = tagT + 1; }
      }
      int guard = 0;
      while (true) {
        unsigned tg = (unsigned)(ld_pkt(pp) >> 32);
        bool ok = isGE ? ((t < 3) || ((int)(tg - want) >= 0)) : (tg == want);
        if (__all(ok)) break;
        if (++guard > (1 << 19)) { dead = true; break; }
      }
      if (dead) break;
    }

    // ---- bulk load + full tag verify (retry on partial arrival) ----
    {
      int guard = 0;
      while (true) {
        bool ok = true;
#pragma unroll
        for (int kk = 0; kk < 8; ++kk) {
          const ull* p4 = hb + hoff(chain, t&3, arow, kk*16 + quad*4);
          ull p0 = ld_pkt(p4+0), p1 = ld_pkt(p4+1), p2 = ld_pkt(p4+2), p3 = ld_pkt(p4+3);
          ok &= ((unsigned)(p0>>32) == tagT) & ((unsigned)(p1>>32) == tagT)
              & ((unsigned)(p2>>32) == tagT) & ((unsigned)(p3>>32) == tagT);
          u32x4v d = { (unsigned)p0, (unsigned)p1, (unsigned)p2, (unsigned)p3 };
          arec[kk] = __builtin_bit_cast(half8, d);
        }
        if (layer == 1) {
          const unsigned tagU = tagT + 1;
#pragma unroll
          for (int kk = 0; kk < 8; ++kk) {
            const ull* p4 = hb + hoff(chain-1, (t+1)&3, arow, kk*16 + quad*4);
            ull p0 = ld_pkt(p4+0), p1 = ld_pkt(p4+1), p2 = ld_pkt(p4+2), p3 = ld_pkt(p4+3);
            ok &= ((unsigned)(p0>>32) == tagU) & ((unsigned)(p1>>32) == tagU)
                & ((unsigned)(p2>>32) == tagU) & ((unsigned)(p3>>32) == tagU);
            u32x4v d = { (unsigned)p0, (unsigned)p1, (unsigned)p2, (unsigned)p3 };
            ain[kk] = __builtin_bit_cast(half8, d);
          }
        }
        if (__all(ok)) break;
        if (++guard > (1 << 16)) { dead = true; break; }
      }
      if (dead) break;
    }

    f32x4 acc0 = {bias[0],bias[0],bias[0],bias[0]};
    f32x4 acc1 = {bias[1],bias[1],bias[1],bias[1]};
    f32x4 acc2 = {bias[2],bias[2],bias[2],bias[2]};
    f32x4 acc3 = {bias[3],bias[3],bias[3],bias[3]};
#pragma unroll
    for (int kk = 0; kk < 8; ++kk) {
      acc0 = __builtin_amdgcn_mfma_f32_16x16x32_f16(ain[kk], bf[0][kk], acc0, 0,0,0);
      acc1 = __builtin_amdgcn_mfma_f32_16x16x32_f16(ain[kk], bf[1][kk], acc1, 0,0,0);
      acc2 = __builtin_amdgcn_mfma_f32_16x16x32_f16(ain[kk], bf[2][kk], acc2, 0,0,0);
      acc3 = __builtin_amdgcn_mfma_f32_16x16x32_f16(ain[kk], bf[3][kk], acc3, 0,0,0);
    }
#pragma unroll
    for (int kk = 0; kk < 8; ++kk) {
      acc0 = __builtin_amdgcn_mfma_f32_16x16x32_f16(arec[kk], bf[0][kk+8], acc0, 0,0,0);
      acc1 = __builtin_amdgcn_mfma_f32_16x16x32_f16(arec[kk], bf[1][kk+8], acc1, 0,0,0);
      acc2 = __builtin_amdgcn_mfma_f32_16x16x32_f16(arec[kk], bf[2][kk+8], acc2, 0,0,0);
      acc3 = __builtin_amdgcn_mfma_f32_16x16x32_f16(arec[kk], bf[3][kk+8], acc3, 0,0,0);
    }

    // LSTM elementwise, fully in-register
    float hval[4];
#pragma unroll
    for (int r = 0; r < 4; ++r) {
      float si = sigmoidf_(acc0[r]);
      float sf = sigmoidf_(acc1[r]);
      float tg = tanhf_  (acc2[r]);
      float so = sigmoidf_(acc3[r]);
      float cn = sf*cst[r] + si*tg;
      cst[r] = cn;
      hval[r] = so*tanhf_(cn);
    }

    // ---- publish h gen t+1 as tagged 8B packets (fire-and-forget) ----
    {
      const unsigned tagN = tagT + 1;
#pragma unroll
      for (int r = 0; r < 4; ++r) {
        float partner = __shfl_xor(hval[r], 1);
        if (!(lq & 1)) {
          unsigned short lo = __builtin_bit_cast(unsigned short, (_Float16)hval[r]);
          unsigned short hi = __builtin_bit_cast(unsigned short, (_Float16)partner);
          unsigned pair = (unsigned)lo | ((unsigned)hi << 16);
          const int row = m*16 + quad*4 + r;
          const int pkt = (c0 + lq) >> 1;
          st_pkt(hb + hoff(chain, (t+1)&3, row, pkt), ((ull)tagN << 32) | pair);
        }
      }
    }

    // out[] stores — off the critical path
    if (layer == 1) {
      const int colg = dir*256 + c0 + lq;
#pragma unroll
      for (int r = 0; r < 4; ++r) {
        const int b = m*16 + quad*4 + r;
        out[((size_t)b*S_ + t)*(2*H_) + colg] = hval[r];
      }
      if (t == S_-1) {
#pragma unroll
        for (int r = 0; r < 4; ++r) {
          const int b = m*16 + quad*4 + r;
          out[OUT0 + (size_t)b*(2*H_) + colg] = hval[r];          // h_last
          out[OUT0 + B_*2*H_ + (size_t)b*(2*H_) + colg] = cst[r]; // c_last
        }
      }
    }
  }
}

extern "C" void kernel_launch(void* const* d_in, const int* in_sizes, int n_in,
                              void* d_out, int out_size, void* d_ws, size_t ws_size,
                              hipStream_t stream) {
  const float* x     = (const float*)d_in[0];
  const float* enc_h = (const float*)d_in[1];
  const float* enc_c = (const float*)d_in[2];
  const float* Wih_f = (const float*)d_in[3];
  const float* Whh_f = (const float*)d_in[4];
  const float* bih_f = (const float*)d_in[5];
  const float* bhh_f = (const float*)d_in[6];
  const float* Wih_b = (const float*)d_in[7];
  const float* Whh_b = (const float*)d_in[8];
  const float* bih_b = (const float*)d_in[9];
  const float* bhh_b = (const float*)d_in[10];

  unsigned* epoch = (unsigned*)((char*)d_ws + 16384);   // persistent counter
  ull* hb         = (ull*)((char*)d_ws + 32768);        // 512 KB packet buffers

  epoch_bump<<<1, 64, 0, stream>>>(epoch);
  lstm_prep<<<64, 256, 0, stream>>>(enc_h, epoch, hb);
  lstm_main<<<128, 64, 0, stream>>>(x, enc_c, Wih_f, Whh_f, bih_f, bhh_f,
                                    Wih_b, Whh_b, bih_b, bhh_b,
                                    (float*)d_out, epoch, hb);
}